// Round 2
// baseline (334.232 us; speedup 1.0000x reference)
//
#include <hip/hip_runtime.h>

#define FFT_N 4096
#define NT 256

// base-4 digit reversal of a 12-bit index (6 digits)
__device__ __forceinline__ int drev12(int p) {
    unsigned b = __brev((unsigned)p) >> 20;                 // bit-reverse 12 bits
    return (int)(((b & 0x555u) << 1) | ((b >> 1) & 0x555u)); // swap bits within pairs
}

__global__ __launch_bounds__(NT) void spectral_circulant_kernel(
    const float* __restrict__ x,
    const float* __restrict__ w_real,
    const float* __restrict__ w_imag,
    const float* __restrict__ bias_p,
    float* __restrict__ out)
{
    __shared__ __align__(16) float re[FFT_N];
    __shared__ __align__(16) float im[FFT_N];
    __shared__ __align__(16) float2 tw[FFT_N / 2];

    const int t   = threadIdx.x;
    const int blk = blockIdx.x;

    // ---- twiddle table: tw[j] = exp(-2*pi*i*j/N), j in [0, N/2) ----
    #pragma unroll
    for (int q = 0; q < (FFT_N / 2) / NT; ++q) {
        int j = t + NT * q;
        float sv, cv;
        sincosf(-6.283185307179586f * ((float)j / (float)FFT_N), &sv, &cv);
        tw[j] = make_float2(cv, sv);
    }

    // ---- load two rows: z = x[2b] + i*x[2b+1] ----
    const float4* __restrict__ xa = (const float4*)(x + (size_t)(2 * blk) * FFT_N);
    const float4* __restrict__ xb = (const float4*)(x + (size_t)(2 * blk + 1) * FFT_N);
    #pragma unroll
    for (int q = 0; q < 4; ++q) {
        int i = t + NT * q;          // float4 index, 0..1023
        float4 a = xa[i];
        float4 b = xb[i];
        *(float4*)&re[4 * i] = a;
        *(float4*)&im[4 * i] = b;
    }
    __syncthreads();

    // ---- forward radix-4 DIF (natural in -> base-4 digit-reversed out) ----
    #pragma unroll
    for (int s = 0; s < 6; ++s) {
        const int L   = FFT_N >> (2 * s);   // 4096,1024,256,64,16,4
        const int Lq  = L >> 2;
        const int twm = FFT_N / L;          // twiddle exponent stride
        #pragma unroll
        for (int bq = 0; bq < 4; ++bq) {
            int idx  = t + NT * bq;         // butterfly id, 0..1023
            int n    = idx & (Lq - 1);
            int sub  = idx / Lq;            // constant-folded to shifts (loop unrolled)
            int base = sub * L + n;

            float ar0 = re[base],          ai0 = im[base];
            float ar1 = re[base + Lq],     ai1 = im[base + Lq];
            float ar2 = re[base + 2 * Lq], ai2 = im[base + 2 * Lq];
            float ar3 = re[base + 3 * Lq], ai3 = im[base + 3 * Lq];

            float t0r = ar0 + ar2, t0i = ai0 + ai2;
            float t1r = ar0 - ar2, t1i = ai0 - ai2;
            float t2r = ar1 + ar3, t2i = ai1 + ai3;
            float t3r = ar1 - ar3, t3i = ai1 - ai3;

            float y0r = t0r + t2r, y0i = t0i + t2i;
            float y2r = t0r - t2r, y2i = t0i - t2i;
            float y1r = t1r + t3i, y1i = t1i - t3r;   // t1 - i*t3
            float y3r = t1r - t3i, y3i = t1i + t3r;   // t1 + i*t3

            int e1 = twm * n;           // < N/4  -> no wrap
            int e2 = e1 + e1;           // < N/2  -> no wrap
            int e3 = e2 + e1;           // < 3N/4 -> may wrap past N/2
            float2 w1 = tw[e1];
            float2 w2 = tw[e2];
            float2 w3 = tw[e3 & (FFT_N / 2 - 1)];
            float sg3 = (e3 & (FFT_N / 2)) ? -1.0f : 1.0f;
            w3.x *= sg3; w3.y *= sg3;

            re[base]          = y0r;
            im[base]          = y0i;
            re[base + Lq]     = y1r * w1.x - y1i * w1.y;
            im[base + Lq]     = y1r * w1.y + y1i * w1.x;
            re[base + 2 * Lq] = y2r * w2.x - y2i * w2.y;
            im[base + 2 * Lq] = y2r * w2.y + y2i * w2.x;
            re[base + 3 * Lq] = y3r * w3.x - y3i * w3.y;
            im[base + 3 * Lq] = y3r * w3.y + y3i * w3.x;
        }
        __syncthreads();
    }

    // ---- pointwise multiply by H[drev(p)] * (1/N)  (spectrum is digit-reversed) ----
    // H[k]: k<1024 -> (wr[k], wi[k]); k in [1024,3072] -> 0 (K-truncation);
    //       k>3072 -> conj of H[4096-k]. 1/N folds ortho^2 and the 4^6 of the inverse.
    const float scale = 1.0f / (float)FFT_N;
    #pragma unroll
    for (int q = 0; q < FFT_N / NT; ++q) {
        int p = t + NT * q;
        int k = drev12(p);
        float hr = 0.0f, hi = 0.0f;
        if (k < 1024) {
            hr = w_real[k];
            hi = w_imag[k];
        } else if (k > 3072) {
            hr = w_real[FFT_N - k];
            hi = -w_imag[FFT_N - k];
        }
        hr *= scale; hi *= scale;
        float zr = re[p], zi = im[p];
        re[p] = zr * hr - zi * hi;
        im[p] = zr * hi + zi * hr;
    }
    __syncthreads();

    // ---- inverse: exact adjoint of the forward graph, run in reverse ----
    // (digit-reversed in -> natural order out; no 1/4 per stage, folded above)
    #pragma unroll
    for (int s = 0; s < 6; ++s) {
        const int L   = 4 << (2 * s);       // 4,16,64,256,1024,4096
        const int Lq  = L >> 2;
        const int twm = FFT_N / L;
        #pragma unroll
        for (int bq = 0; bq < 4; ++bq) {
            int idx  = t + NT * bq;
            int n    = idx & (Lq - 1);
            int sub  = idx / Lq;
            int base = sub * L + n;

            float y0r = re[base],          y0i = im[base];
            float u1r = re[base + Lq],     u1i = im[base + Lq];
            float u2r = re[base + 2 * Lq], u2i = im[base + 2 * Lq];
            float u3r = re[base + 3 * Lq], u3i = im[base + 3 * Lq];

            int e1 = twm * n;
            int e2 = e1 + e1;
            int e3 = e2 + e1;
            float2 w1 = tw[e1];
            float2 w2 = tw[e2];
            float2 w3 = tw[e3 & (FFT_N / 2 - 1)];
            float sg3 = (e3 & (FFT_N / 2)) ? -1.0f : 1.0f;
            w3.x *= sg3; w3.y *= sg3;

            // un-twiddle: multiply by conj(w) = (c, -s)
            float y1r = u1r * w1.x + u1i * w1.y, y1i = u1i * w1.x - u1r * w1.y;
            float y2r = u2r * w2.x + u2i * w2.y, y2i = u2i * w2.x - u2r * w2.y;
            float y3r = u3r * w3.x + u3i * w3.y, y3i = u3i * w3.x - u3r * w3.y;

            float t0r = y0r + y2r, t0i = y0i + y2i;
            float t1r = y0r - y2r, t1i = y0i - y2i;
            float t2r = y1r + y3r, t2i = y1i + y3i;
            float t3r = y1r - y3r, t3i = y1i - y3i;

            float a0r = t0r + t2r, a0i = t0i + t2i;
            float a2r = t0r - t2r, a2i = t0i - t2i;
            float a1r = t1r - t3i, a1i = t1i + t3r;   // t1 + i*t3
            float a3r = t1r + t3i, a3i = t1i - t3r;   // t1 - i*t3

            re[base]          = a0r;  im[base]          = a0i;
            re[base + Lq]     = a1r;  im[base + Lq]     = a1i;
            re[base + 2 * Lq] = a2r;  im[base + 2 * Lq] = a2i;
            re[base + 3 * Lq] = a3r;  im[base + 3 * Lq] = a3i;
        }
        __syncthreads();
    }

    // ---- store: y1 = Re(w) + bias, y2 = Im(w) + bias ----
    const float bv = bias_p[0];
    float4* __restrict__ oa = (float4*)(out + (size_t)(2 * blk) * FFT_N);
    float4* __restrict__ ob = (float4*)(out + (size_t)(2 * blk + 1) * FFT_N);
    #pragma unroll
    for (int q = 0; q < 4; ++q) {
        int i = t + NT * q;
        float4 a = *(const float4*)&re[4 * i];
        float4 b = *(const float4*)&im[4 * i];
        a.x += bv; a.y += bv; a.z += bv; a.w += bv;
        b.x += bv; b.y += bv; b.z += bv; b.w += bv;
        oa[i] = a;
        ob[i] = b;
    }
}

extern "C" void kernel_launch(void* const* d_in, const int* in_sizes, int n_in,
                              void* d_out, int out_size, void* d_ws, size_t ws_size,
                              hipStream_t stream) {
    (void)in_sizes; (void)n_in; (void)d_ws; (void)ws_size; (void)out_size;
    const float* x      = (const float*)d_in[0];   // (8192, 4096) f32
    const float* w_real = (const float*)d_in[1];   // (2049,) f32
    const float* w_imag = (const float*)d_in[2];   // (2049,) f32
    const float* bias   = (const float*)d_in[3];   // scalar f32
    float* out = (float*)d_out;                    // (8192, 4096) f32

    // one block per row-pair (two real rows packed into one complex FFT)
    spectral_circulant_kernel<<<8192 / 2, NT, 0, stream>>>(x, w_real, w_imag, bias, out);
}

// Round 3
// 243.855 us; speedup vs baseline: 1.3706x; 1.3706x over previous
//
#include <hip/hip_runtime.h>

#define NT 256
// LDS swizzle: +1 float pad per 32 -> all exchange patterns <=2 lanes/bank (free)
#define PHYS_PAD(l) ((l) + ((l) >> 5))

// 16-point DFT in registers: v[k] = sum_j v[j] * w16^{jk}, w16 = e^{-2pi i/16}
// (INV=true: conjugated, i.e. e^{+2pi i/16}; unnormalized). Natural order in/out.
template<bool INV>
__device__ __forceinline__ void dft16(float* vr, float* vi) {
    constexpr float C1 = 0.9238795325112867f;   // cos(pi/8)
    constexpr float S1 = 0.3826834323650898f;   // sin(pi/8)
    constexpr float HF = 0.7071067811865476f;
    // forward w16^e = (WR[e], WI[e]); e = jl*k4 in {1,2,3,4,6,9}
    const float WR[10] = {1.f,  C1,  HF,  S1, 0.f, 0.f, -HF, 0.f, 0.f, -C1};
    const float WI[10] = {0.f, -S1, -HF, -C1, -1.f, 0.f, -HF, 0.f, 0.f,  S1};

    float ar[16], ai[16];
    // stage 1: DFT-4 over jh within groups {jl, jl+4, jl+8, jl+12} -> A_{jl}[k4] at [jl+4*k4]
    #pragma unroll
    for (int jl = 0; jl < 4; ++jl) {
        float x0r = vr[jl],      x0i = vi[jl];
        float x1r = vr[jl + 4],  x1i = vi[jl + 4];
        float x2r = vr[jl + 8],  x2i = vi[jl + 8];
        float x3r = vr[jl + 12], x3i = vi[jl + 12];
        float t0r = x0r + x2r, t0i = x0i + x2i;
        float t1r = x0r - x2r, t1i = x0i - x2i;
        float t2r = x1r + x3r, t2i = x1i + x3i;
        float t3r = x1r - x3r, t3i = x1i - x3i;
        ar[jl]     = t0r + t2r;  ai[jl]     = t0i + t2i;
        ar[jl + 8] = t0r - t2r;  ai[jl + 8] = t0i - t2i;
        if (!INV) {
            ar[jl + 4]  = t1r + t3i;  ai[jl + 4]  = t1i - t3r;  // t1 - i*t3
            ar[jl + 12] = t1r - t3i;  ai[jl + 12] = t1i + t3r;  // t1 + i*t3
        } else {
            ar[jl + 4]  = t1r - t3i;  ai[jl + 4]  = t1i + t3r;
            ar[jl + 12] = t1r + t3i;  ai[jl + 12] = t1i - t3r;
        }
    }
    // twiddle: a[jl+4k4] *= w16^{+/- jl*k4}
    #pragma unroll
    for (int k4 = 1; k4 < 4; ++k4) {
        #pragma unroll
        for (int jl = 1; jl < 4; ++jl) {
            const int e = jl * k4;
            float wr = WR[e];
            float wi = INV ? -WI[e] : WI[e];
            const int id = jl + 4 * k4;
            float xr = ar[id], xi = ai[id];
            ar[id] = xr * wr - xi * wi;
            ai[id] = xr * wi + xi * wr;
        }
    }
    // stage 2: DFT-4 over jl within groups {4k4..4k4+3} -> y[k4 + 4*kh] (natural order)
    #pragma unroll
    for (int k4 = 0; k4 < 4; ++k4) {
        float x0r = ar[4*k4 + 0], x0i = ai[4*k4 + 0];
        float x1r = ar[4*k4 + 1], x1i = ai[4*k4 + 1];
        float x2r = ar[4*k4 + 2], x2i = ai[4*k4 + 2];
        float x3r = ar[4*k4 + 3], x3i = ai[4*k4 + 3];
        float t0r = x0r + x2r, t0i = x0i + x2i;
        float t1r = x0r - x2r, t1i = x0i - x2i;
        float t2r = x1r + x3r, t2i = x1i + x3i;
        float t3r = x1r - x3r, t3i = x1i - x3i;
        vr[k4]     = t0r + t2r;  vi[k4]     = t0i + t2i;
        vr[k4 + 8] = t0r - t2r;  vi[k4 + 8] = t0i - t2i;
        if (!INV) {
            vr[k4 + 4]  = t1r + t3i;  vi[k4 + 4]  = t1i - t3r;
            vr[k4 + 12] = t1r - t3i;  vi[k4 + 12] = t1i + t3r;
        } else {
            vr[k4 + 4]  = t1r - t3i;  vi[k4 + 4]  = t1i + t3r;
            vr[k4 + 12] = t1r + t3i;  vi[k4 + 12] = t1i - t3r;
        }
    }
}

// apply v[e] *= (wr,wi)^e for e=1..15 by iterative powering
__device__ __forceinline__ void apply_tw_powers(float* vr, float* vi, float wr, float wi) {
    float pr = wr, pi = wi;
    #pragma unroll
    for (int e = 1; e < 16; ++e) {
        float xr = vr[e], xi = vi[e];
        vr[e] = xr * pr - xi * pi;
        vi[e] = xr * pi + xi * pr;
        float nr = pr * wr - pi * wi;
        float ni = pr * wi + pi * wr;
        pr = nr; pi = ni;
    }
}

__global__ __launch_bounds__(NT, 4) void spectral_circulant_r16(
    const float* __restrict__ x,
    const float* __restrict__ w_real,
    const float* __restrict__ w_imag,
    const float* __restrict__ bias_p,
    float* __restrict__ out)
{
    __shared__ float lre[4224];   // PHYS_PAD(4095)=4222
    __shared__ float lim[4224];

    const int t   = threadIdx.x;
    const int blk = blockIdx.x;

    float vr[16], vi[16];

    // ---- load two rows: z = rowA + i*rowB; reg j holds x[256j + t] ----
    const float* __restrict__ xa = x + (size_t)(2 * blk) * 4096;
    const float* __restrict__ xb = xa + 4096;
    #pragma unroll
    for (int j = 0; j < 16; ++j) {
        vr[j] = xa[(j << 8) + t];
        vi[j] = xb[(j << 8) + t];
    }

    // ---- stage A: DFT16 over j -> digit a; twiddle W4096^{t*a} ----
    dft16<false>(vr, vi);
    float sA, cA;
    __sincosf((float)t * -1.5339807878856412e-3f, &sA, &cA);  // -2pi/4096
    apply_tw_powers(vr, vi, cA, sA);

    // ---- exchange 1 write: l = 256a + t ----
    {
        const int b0 = t + (t >> 5);
        #pragma unroll
        for (int a = 0; a < 16; ++a) {
            lre[b0 + 264 * a] = vr[a];
            lim[b0 + 264 * a] = vi[a];
        }
    }
    __syncthreads();

    const int ax = t >> 4;           // 'a' digit handled by this thread in stage B
    const int m2 = t & 15;           // 'm2' digit
    const int base1 = 264 * ax + m2; // PHYS_PAD(256*ax + 16*q + m2) = base1 + 16q + (q>>1)

    // ---- exchange 1 read: over j2 ----
    #pragma unroll
    for (int q = 0; q < 16; ++q) {
        const int ad = base1 + 16 * q + (q >> 1);
        vr[q] = lre[ad];
        vi[q] = lim[ad];
    }

    // ---- stage B: DFT16 over j2 -> digit b; twiddle W256^{m2*b} ----
    dft16<false>(vr, vi);
    float sB, cB;
    __sincosf((float)m2 * -2.454369260617026e-2f, &sB, &cB);  // -2pi/256
    apply_tw_powers(vr, vi, cB, sB);

    // ---- exchange 2 write: l = 256*ax + 16*b + m2 (same physical set as ex1 read) ----
    #pragma unroll
    for (int b = 0; b < 16; ++b) {
        const int ad = base1 + 16 * b + (b >> 1);
        lre[ad] = vr[b];
        lim[ad] = vi[b];
    }
    __syncthreads();

    const int a2 = t >> 4;           // 'a' digit for stage C
    const int bb = t & 15;           // 'b' digit for stage C
    const int base2 = 264 * a2 + 16 * bb + (bb >> 1);

    // ---- exchange 2 read: over m2' (contiguous) ----
    #pragma unroll
    for (int m = 0; m < 16; ++m) {
        vr[m] = lre[base2 + m];
        vi[m] = lim[base2 + m];
    }

    // ---- stage C: DFT16 over m2' -> digit r3; freq k = 256*r3 + 16*bb + a2 ----
    dft16<false>(vr, vi);

    // ---- pointwise H[k]/N ----
    {
        const int c = (bb << 4) | a2;            // 16*b + a  in [0,255]
        const float sc = 1.0f / 4096.0f;
        #pragma unroll
        for (int r3 = 0; r3 < 4; ++r3) {         // k = 256*r3 + c < 1024: active
            const int k = (r3 << 8) + c;
            float hr = w_real[k] * sc;
            float hi = w_imag[k] * sc;
            float xr = vr[r3], xi = vi[r3];
            vr[r3] = xr * hr - xi * hi;
            vi[r3] = xr * hi + xi * hr;
        }
        #pragma unroll
        for (int r3 = 4; r3 < 12; ++r3) {        // k in [1024,3071]: truncated
            vr[r3] = 0.0f; vi[r3] = 0.0f;
        }
        {                                        // r3=12: k=3072+c, active iff c>0
            const int idx = 1024 - c;            // c=0 -> idx=1024 (valid load, masked)
            const float m = (c > 0) ? sc : 0.0f;
            float hr = w_real[idx] * m;
            float hi = -w_imag[idx] * m;
            float xr = vr[12], xi = vi[12];
            vr[12] = xr * hr - xi * hi;
            vi[12] = xr * hi + xi * hr;
        }
        #pragma unroll
        for (int r3 = 13; r3 < 16; ++r3) {       // k > 3072: conj mirror
            const int idx = ((16 - r3) << 8) - c;
            float hr = w_real[idx] * sc;
            float hi = -w_imag[idx] * sc;
            float xr = vr[r3], xi = vi[r3];
            vr[r3] = xr * hr - xi * hi;
            vi[r3] = xr * hi + xi * hr;
        }
    }

    // ================= inverse: exact adjoint, reverse order =================

    // ---- C^H: conj DFT16 over r3 -> m2' ----
    dft16<true>(vr, vi);

    // ---- exchange 2 reverse write (same addresses this thread read) ----
    #pragma unroll
    for (int m = 0; m < 16; ++m) {
        lre[base2 + m] = vr[m];
        lim[base2 + m] = vi[m];
    }
    __syncthreads();

    // ---- exchange 2 reverse read: over b ----
    #pragma unroll
    for (int b = 0; b < 16; ++b) {
        const int ad = base1 + 16 * b + (b >> 1);
        vr[b] = lre[ad];
        vi[b] = lim[ad];
    }

    // ---- B^H: conj twiddle W256^{+m2*b}, then conj DFT16 over b -> j2 ----
    apply_tw_powers(vr, vi, cB, -sB);
    dft16<true>(vr, vi);

    // ---- exchange 1 reverse write: l = 256*ax + 16*j2 + m2 (same set) ----
    #pragma unroll
    for (int q = 0; q < 16; ++q) {
        const int ad = base1 + 16 * q + (q >> 1);
        lre[ad] = vr[q];
        lim[ad] = vi[q];
    }
    __syncthreads();

    // ---- exchange 1 reverse read: over a ----
    {
        const int b0 = t + (t >> 5);
        #pragma unroll
        for (int a = 0; a < 16; ++a) {
            vr[a] = lre[b0 + 264 * a];
            vi[a] = lim[b0 + 264 * a];
        }
    }

    // ---- A^H: conj twiddle W4096^{+t*a}, then conj DFT16 over a -> j ----
    apply_tw_powers(vr, vi, cA, -sA);
    dft16<true>(vr, vi);

    // ---- store: rowA = Re + bias, rowB = Im + bias ----
    const float bv = bias_p[0];
    float* __restrict__ oa = out + (size_t)(2 * blk) * 4096;
    float* __restrict__ ob = oa + 4096;
    #pragma unroll
    for (int j = 0; j < 16; ++j) {
        oa[(j << 8) + t] = vr[j] + bv;
        ob[(j << 8) + t] = vi[j] + bv;
    }
}

extern "C" void kernel_launch(void* const* d_in, const int* in_sizes, int n_in,
                              void* d_out, int out_size, void* d_ws, size_t ws_size,
                              hipStream_t stream) {
    (void)in_sizes; (void)n_in; (void)d_ws; (void)ws_size; (void)out_size;
    const float* x      = (const float*)d_in[0];   // (8192, 4096) f32
    const float* w_real = (const float*)d_in[1];   // (2049,) f32
    const float* w_imag = (const float*)d_in[2];   // (2049,) f32
    const float* bias   = (const float*)d_in[3];   // scalar f32
    float* out = (float*)d_out;                    // (8192, 4096) f32

    spectral_circulant_r16<<<8192 / 2, NT, 0, stream>>>(x, w_real, w_imag, bias, out);
}

// Round 5
// 240.354 us; speedup vs baseline: 1.3906x; 1.0146x over previous
//
#include <hip/hip_runtime.h>

#define NT 256

// LDS physical layout in float2 units: PH(l) = l + 2*(l>>4).
// - order-preserving & contiguous within every aligned 16-block (l>>4 const)
// - block starts PH(16k)=18k even -> 16B aligned for b128
// - breaks the all-lanes-same-bank pattern of the contiguous exchange-2 access
__device__ __forceinline__ int PH(int l) { return l + 2 * (l >> 4); }

// 16-point DFT in registers: v[k] = sum_j v[j] * w16^{jk}, w16 = e^{-2pi i/16}
// (INV=true: conjugated; unnormalized). Natural order in/out.
template<bool INV>
__device__ __forceinline__ void dft16(float* vr, float* vi) {
    constexpr float C1 = 0.9238795325112867f;   // cos(pi/8)
    constexpr float S1 = 0.3826834323650898f;   // sin(pi/8)
    constexpr float HF = 0.7071067811865476f;
    const float WR[10] = {1.f,  C1,  HF,  S1, 0.f, 0.f, -HF, 0.f, 0.f, -C1};
    const float WI[10] = {0.f, -S1, -HF, -C1, -1.f, 0.f, -HF, 0.f, 0.f,  S1};

    float ar[16], ai[16];
    #pragma unroll
    for (int jl = 0; jl < 4; ++jl) {
        float x0r = vr[jl],      x0i = vi[jl];
        float x1r = vr[jl + 4],  x1i = vi[jl + 4];
        float x2r = vr[jl + 8],  x2i = vi[jl + 8];
        float x3r = vr[jl + 12], x3i = vi[jl + 12];
        float t0r = x0r + x2r, t0i = x0i + x2i;
        float t1r = x0r - x2r, t1i = x0i - x2i;
        float t2r = x1r + x3r, t2i = x1i + x3i;
        float t3r = x1r - x3r, t3i = x1i - x3i;
        ar[jl]     = t0r + t2r;  ai[jl]     = t0i + t2i;
        ar[jl + 8] = t0r - t2r;  ai[jl + 8] = t0i - t2i;
        if (!INV) {
            ar[jl + 4]  = t1r + t3i;  ai[jl + 4]  = t1i - t3r;  // t1 - i*t3
            ar[jl + 12] = t1r - t3i;  ai[jl + 12] = t1i + t3r;  // t1 + i*t3
        } else {
            ar[jl + 4]  = t1r - t3i;  ai[jl + 4]  = t1i + t3r;
            ar[jl + 12] = t1r + t3i;  ai[jl + 12] = t1i - t3r;
        }
    }
    #pragma unroll
    for (int k4 = 1; k4 < 4; ++k4) {
        #pragma unroll
        for (int jl = 1; jl < 4; ++jl) {
            const int e = jl * k4;
            float wr = WR[e];
            float wi = INV ? -WI[e] : WI[e];
            const int id = jl + 4 * k4;
            float xr = ar[id], xi = ai[id];
            ar[id] = xr * wr - xi * wi;
            ai[id] = xr * wi + xi * wr;
        }
    }
    #pragma unroll
    for (int k4 = 0; k4 < 4; ++k4) {
        float x0r = ar[4*k4 + 0], x0i = ai[4*k4 + 0];
        float x1r = ar[4*k4 + 1], x1i = ai[4*k4 + 1];
        float x2r = ar[4*k4 + 2], x2i = ai[4*k4 + 2];
        float x3r = ar[4*k4 + 3], x3i = ai[4*k4 + 3];
        float t0r = x0r + x2r, t0i = x0i + x2i;
        float t1r = x0r - x2r, t1i = x0i - x2i;
        float t2r = x1r + x3r, t2i = x1i + x3i;
        float t3r = x1r - x3r, t3i = x1i - x3i;
        vr[k4]     = t0r + t2r;  vi[k4]     = t0i + t2i;
        vr[k4 + 8] = t0r - t2r;  vi[k4 + 8] = t0i - t2i;
        if (!INV) {
            vr[k4 + 4]  = t1r + t3i;  vi[k4 + 4]  = t1i - t3r;
            vr[k4 + 12] = t1r - t3i;  vi[k4 + 12] = t1i + t3r;
        } else {
            vr[k4 + 4]  = t1r - t3i;  vi[k4 + 4]  = t1i + t3r;
            vr[k4 + 12] = t1r + t3i;  vi[k4 + 12] = t1i - t3r;
        }
    }
}

// v[e] *= (wr,wi)^e for e=1..15; two independent chains stepping by w^2
// (halves the serial complex-mul chain latency vs a single chain).
__device__ __forceinline__ void apply_tw_powers(float* vr, float* vi, float wr, float wi) {
    const float w2r = wr * wr - wi * wi;
    const float w2i = 2.0f * wr * wi;
    float aor = wr,  aoi = wi;    // odd powers: w^1, w^3, ...
    float aer = w2r, aei = w2i;   // even powers: w^2, w^4, ...
    #pragma unroll
    for (int e = 1; e < 16; e += 2) {
        { float xr = vr[e], xi = vi[e];
          vr[e] = xr * aor - xi * aoi;
          vi[e] = xr * aoi + xi * aor; }
        if (e + 1 < 16) {
            float xr = vr[e + 1], xi = vi[e + 1];
            vr[e + 1] = xr * aer - xi * aei;
            vi[e + 1] = xr * aei + xi * aer;
        }
        if (e + 2 < 16) {
            float nr = aor * w2r - aoi * w2i, ni = aor * w2i + aoi * w2r;
            aor = nr; aoi = ni;
            nr = aer * w2r - aei * w2i; ni = aer * w2i + aei * w2r;
            aer = nr; aei = ni;
        }
    }
}

__global__ __launch_bounds__(NT, 4) void spectral_circulant_r16v3(
    const float* __restrict__ x,
    const float* __restrict__ w_real,
    const float* __restrict__ w_imag,
    const float* __restrict__ bias_p,
    float* __restrict__ out)
{
    __shared__ __align__(16) float2 lds[4606];   // PH(4095)=4605 -> 36.8 KB, 4 blocks/CU

    const int t   = threadIdx.x;
    const int blk = blockIdx.x;

    float vr[16], vi[16];

    // ---- load two rows: z = rowA + i*rowB; reg j holds x[256j + t] ----
    const float* __restrict__ xa = x + (size_t)(2 * blk) * 4096;
    const float* __restrict__ xb = xa + 4096;
    #pragma unroll
    for (int j = 0; j < 16; ++j) {
        vr[j] = xa[(j << 8) + t];
        vi[j] = xb[(j << 8) + t];
    }

    // ---- stage A: DFT16 over j -> digit a; twiddle W4096^{t*a} ----
    dft16<false>(vr, vi);
    float sA, cA;
    __sincosf((float)t * -1.5339807878856412e-3f, &sA, &cA);  // -2pi/4096
    apply_tw_powers(vr, vi, cA, sA);

    // ---- exchange 1 write: l = 256a + t (b64); PH = 288a + tp ----
    {
        const int tp = t + 2 * (t >> 4);
        #pragma unroll
        for (int a = 0; a < 16; ++a)
            lds[288 * a + tp] = make_float2(vr[a], vi[a]);
    }
    __syncthreads();

    const int ax = t >> 4;               // upper digit this thread owns from here on
    const int m2 = t & 15;               // lower digit
    const int base = 288 * ax + m2;      // PH(256ax + 16q + m2) = base + 18q

    // ---- exchange 1 read: l = 256ax + 16q + m2 (b64) ----
    #pragma unroll
    for (int q = 0; q < 16; ++q) {
        float2 v = lds[base + 18 * q];
        vr[q] = v.x; vi[q] = v.y;
    }

    // ---- stage B: DFT16 over q -> digit b; twiddle W256^{m2*b} ----
    dft16<false>(vr, vi);
    float sB, cB;
    __sincosf((float)m2 * -2.454369260617026e-2f, &sB, &cB);  // -2pi/256
    apply_tw_powers(vr, vi, cB, sB);

    // ---- exchange 2 write: l = 256ax + 16b + m2 (b64) — same set this thread
    // read. Moves data only within 16 consecutive threads (same wave): per-wave
    // in-order DS pipe + compiler scheduling barrier suffice, no block barrier.
    #pragma unroll
    for (int b = 0; b < 16; ++b)
        lds[base + 18 * b] = make_float2(vr[b], vi[b]);
    __builtin_amdgcn_wave_barrier();

    // ---- exchange 2 read: 16 contiguous at l0 = 256ax + 16*m2; PH order-preserving,
    // start PH(l0) = 288ax + 18*m2 (even -> 16B aligned) (b128) ----
    const float4* __restrict__ pfr = (const float4*)&lds[288 * ax + 18 * m2];
    #pragma unroll
    for (int m = 0; m < 16; m += 2) {
        float4 v = pfr[m >> 1];
        vr[m] = v.x;     vi[m] = v.y;
        vr[m + 1] = v.z; vi[m + 1] = v.w;
    }

    // ---- stage C: DFT16 over m -> digit r3; freq k = 256*r3 + 16*m2 + ax ----
    dft16<false>(vr, vi);

    // ---- pointwise H[k]/N ----
    {
        const int c = (m2 << 4) | ax;            // 16*b + a  in [0,255]
        const float sc = 1.0f / 4096.0f;
        #pragma unroll
        for (int r3 = 0; r3 < 4; ++r3) {         // k < 1024: active
            const int k = (r3 << 8) + c;
            float hr = w_real[k] * sc;
            float hi = w_imag[k] * sc;
            float xr = vr[r3], xi = vi[r3];
            vr[r3] = xr * hr - xi * hi;
            vi[r3] = xr * hi + xi * hr;
        }
        #pragma unroll
        for (int r3 = 4; r3 < 12; ++r3) {        // k in [1024,3071]: truncated
            vr[r3] = 0.0f; vi[r3] = 0.0f;
        }
        {                                        // r3=12: k=3072+c, active iff c>0
            const int idx = 1024 - c;
            const float m = (c > 0) ? sc : 0.0f;
            float hr = w_real[idx] * m;
            float hi = -w_imag[idx] * m;
            float xr = vr[12], xi = vi[12];
            vr[12] = xr * hr - xi * hi;
            vi[12] = xr * hi + xi * hr;
        }
        #pragma unroll
        for (int r3 = 13; r3 < 16; ++r3) {       // k > 3072: conj mirror
            const int idx = ((16 - r3) << 8) - c;
            float hr = w_real[idx] * sc;
            float hi = -w_imag[idx] * sc;
            float xr = vr[r3], xi = vi[r3];
            vr[r3] = xr * hr - xi * hi;
            vi[r3] = xr * hi + xi * hr;
        }
    }

    // ================= inverse: exact adjoint, reverse order =================

    // ---- C^H: conj DFT16 over r3 -> m ----
    dft16<true>(vr, vi);

    // ---- exchange 2 reverse write: same contiguous addresses (b128) ----
    {
        float4* __restrict__ pfw = (float4*)&lds[288 * ax + 18 * m2];
        #pragma unroll
        for (int m = 0; m < 16; m += 2)
            pfw[m >> 1] = make_float4(vr[m], vi[m], vr[m + 1], vi[m + 1]);
    }
    __builtin_amdgcn_wave_barrier();

    // ---- exchange 2 reverse read: l = 256ax + 16b + m2 over b (b64) ----
    #pragma unroll
    for (int b = 0; b < 16; ++b) {
        float2 v = lds[base + 18 * b];
        vr[b] = v.x; vi[b] = v.y;
    }

    // ---- B^H: conj twiddle, conj DFT16 over b -> q ----
    apply_tw_powers(vr, vi, cB, -sB);
    dft16<true>(vr, vi);

    // ---- exchange 1 reverse write: l = 256ax + 16q + m2 (same set, b64) ----
    #pragma unroll
    for (int q = 0; q < 16; ++q)
        lds[base + 18 * q] = make_float2(vr[q], vi[q]);
    __syncthreads();

    // ---- exchange 1 reverse read: l = 256a + t (b64) ----
    {
        const int tp = t + 2 * (t >> 4);
        #pragma unroll
        for (int a = 0; a < 16; ++a) {
            float2 v = lds[288 * a + tp];
            vr[a] = v.x; vi[a] = v.y;
        }
    }

    // ---- A^H: conj twiddle, conj DFT16 over a -> j ----
    apply_tw_powers(vr, vi, cA, -sA);
    dft16<true>(vr, vi);

    // ---- store (nontemporal: streamed output) ----
    const float bv = bias_p[0];
    float* __restrict__ oa = out + (size_t)(2 * blk) * 4096;
    float* __restrict__ ob = oa + 4096;
    #pragma unroll
    for (int j = 0; j < 16; ++j) {
        __builtin_nontemporal_store(vr[j] + bv, &oa[(j << 8) + t]);
        __builtin_nontemporal_store(vi[j] + bv, &ob[(j << 8) + t]);
    }
}

extern "C" void kernel_launch(void* const* d_in, const int* in_sizes, int n_in,
                              void* d_out, int out_size, void* d_ws, size_t ws_size,
                              hipStream_t stream) {
    (void)in_sizes; (void)n_in; (void)d_ws; (void)ws_size; (void)out_size;
    const float* x      = (const float*)d_in[0];   // (8192, 4096) f32
    const float* w_real = (const float*)d_in[1];   // (2049,) f32
    const float* w_imag = (const float*)d_in[2];   // (2049,) f32
    const float* bias   = (const float*)d_in[3];   // scalar f32
    float* out = (float*)d_out;                    // (8192, 4096) f32

    spectral_circulant_r16v3<<<8192 / 2, NT, 0, stream>>>(x, w_real, w_imag, bias, out);
}